// Round 22
// baseline (45.967 us; speedup 1.0000x reference)
//
#include <hip/hip_runtime.h>
#include <hip/hip_bf16.h>
#include <math.h>

#define B_ 4
#define S_ 2048
#define D_ 256
#define H_ 8

typedef __attribute__((ext_vector_type(8))) __bf16 bf16x8;
typedef __attribute__((ext_vector_type(4))) float f32x4;

__device__ inline ushort f2bf(float x) {
  unsigned u = __builtin_bit_cast(unsigned, x);
  unsigned r = u + 0x7fffu + ((u >> 16) & 1u);
  return (ushort)(r >> 16);
}

__device__ inline float bf2f(ushort u) {
  unsigned v = ((unsigned)u) << 16;
  return __builtin_bit_cast(float, v);
}

__device__ inline unsigned cvtpk(float lo, float hi) {
  unsigned r;
  asm("v_cvt_pk_bf16_f32 %0, %1, %2" : "=v"(r) : "v"(lo), "v"(hi));
  return r;
}

__device__ inline bf16x8 load8(const ushort* p) {
  return __builtin_bit_cast(bf16x8, *(const uint4*)p);
}

// sqrt(RS * log2e); scores from scaled Q,K are C1*s directly; fixed offset cancels.
#define SC_ 0.7788317f

// ---- unified prepass (green R20 verbatim): grid (64, 33) ----
__global__ __launch_bounds__(256) void prep_kernel(
    const float* __restrict__ x, const float* __restrict__ mask,
    const float* __restrict__ pos, const float* __restrict__ w,
    ushort* __restrict__ posbf, ushort* __restrict__ frag,
    ushort* __restrict__ maskp, ushort* __restrict__ wfrag) {
  __shared__ float Lx[32][33];
  __shared__ ushort Wt[32][33];
  const int T = blockIdx.x, bh = blockIdx.y;
  const int tid = threadIdx.x;

  if (bh == 32) {
    int ks = T & 7, np = T >> 3;
    int k0 = ks * 32, n0 = np * 32;
#pragma unroll
    for (int k = 0; k < 4; ++k) {
      int idx = tid + k * 256;  // 0..1023
      int ty = idx >> 5, tx = idx & 31;
      Wt[ty][tx] = f2bf(w[(k0 + ty) * D_ + n0 + tx]);
    }
    __syncthreads();
    if (tid < 128) {
      int sub = tid >> 6, lane = tid & 63;
      int c = lane & 15, g = lane >> 4;
      int nt = np * 2 + sub;
      ushort e[8];
#pragma unroll
      for (int i = 0; i < 8; ++i) e[i] = Wt[g * 8 + i][sub * 16 + c];
      uint4 fr;
      fr.x = (unsigned)e[0] | ((unsigned)e[1] << 16);
      fr.y = (unsigned)e[2] | ((unsigned)e[3] << 16);
      fr.z = (unsigned)e[4] | ((unsigned)e[5] << 16);
      fr.w = (unsigned)e[6] | ((unsigned)e[7] << 16);
      *(uint4*)(wfrag + ((size_t)(nt * 8 + ks) * 64 + lane) * 8) = fr;
    }
    return;
  }

  const int b = bh >> 3, h = bh & 7;
  const int slot = tid >> 6, lane = tid & 63;
  const int c = lane & 15, g = lane >> 4;
  const size_t rb = (size_t)(b * S_) + T * 32;  // global row base

  // (a) x * mask -> LDS f32 tile (float4 loads)
  {
    int row = tid >> 3, c4 = tid & 7;
    float mv = mask[rb + row];
    float4 v = *(const float4*)(x + (rb + row) * D_ + h * 32 + c4 * 4);
    Lx[row][c4 * 4 + 0] = v.x * mv;
    Lx[row][c4 * 4 + 1] = v.y * mv;
    Lx[row][c4 * 4 + 2] = v.z * mv;
    Lx[row][c4 * 4 + 3] = v.w * mv;
  }

  // (b) K slots: pos scaled by SC_
  if (slot < 2) {
    int row = slot * 16 + c;
    const float* ps = pos + (rb + row) * D_ + h * 32 + g * 8;
    float4 v0 = *(const float4*)ps;
    float4 v1 = *(const float4*)(ps + 4);
    uint4 fr;
    fr.x = (unsigned)f2bf(v0.x * SC_) | ((unsigned)f2bf(v0.y * SC_) << 16);
    fr.y = (unsigned)f2bf(v0.z * SC_) | ((unsigned)f2bf(v0.w * SC_) << 16);
    fr.z = (unsigned)f2bf(v1.x * SC_) | ((unsigned)f2bf(v1.y * SC_) << 16);
    fr.w = (unsigned)f2bf(v1.z * SC_) | ((unsigned)f2bf(v1.w * SC_) << 16);
    *(uint4*)(frag + ((size_t)(bh * 64 + T) * 4 + slot) * 512 + lane * 8) = fr;
    *(uint4*)(posbf + (rb + row) * D_ + h * 32 + g * 8) = fr;
  }

  __syncthreads();

  // (c) V slots
  if (slot >= 2) {
    int dcol = (slot - 2) * 16 + c;
    ushort e[8];
#pragma unroll
    for (int i = 0; i < 8; ++i) {
      int key = (i < 4) ? (4 * g + i) : (16 + 4 * g + (i - 4));  // kappa(g*8+i)
      e[i] = f2bf(Lx[key][dcol]);
    }
    uint4 fr;
    fr.x = (unsigned)e[0] | ((unsigned)e[1] << 16);
    fr.y = (unsigned)e[2] | ((unsigned)e[3] << 16);
    fr.z = (unsigned)e[4] | ((unsigned)e[5] << 16);
    fr.w = (unsigned)e[6] | ((unsigned)e[7] << 16);
    *(uint4*)(frag + ((size_t)(bh * 64 + T) * 4 + slot) * 512 + lane * 8) = fr;
  }

  // (d) kappa-permuted bf16 mask
  if (h == 0 && tid < 32) {
    int t = tid;
    int kx = ((t >> 1) & 12) + (t & 3) + ((t & 4) << 2);
    maskp[rb + t] = f2bf(mask[rb + kx]);
  }
}

// ---- flash attention: 128 q per wave (j-loop 8), in-block split-K x4, grid 512 ----
__global__ __launch_bounds__(256, 2) void attn_kernel(
    const ushort* __restrict__ posbf,
    const ushort* __restrict__ frag,
    const ushort* __restrict__ maskp,
    ushort* __restrict__ attnbf) {
  __shared__ ushort lo[4][128][32];  // [wave][q][d] bf16 partial outputs
  __shared__ float ll[4][128];       // [wave][q] partial lsums (f32)
  __shared__ float linv[128];

  const int tid = threadIdx.x;
  const int wid = tid >> 6, lane = tid & 63;
  const int c = lane & 15, g = lane >> 4;
  const int blk = blockIdx.x;
  const int bh = blk & 31;   // XCD co-location
  const int qc = blk >> 5;   // 0..15
  const int b = bh >> 3, h = bh & 7;
  const int q0 = qc * 128;
  const int koff = wid * 512;

  const ushort* posb = posbf + (size_t)b * S_ * D_;

  // 8 Q fragments: chunk j covers queries q0+16j+c
  bf16x8 fq[8];
#pragma unroll
  for (int j = 0; j < 8; ++j)
    fq[j] = load8(posb + (size_t)(q0 + 16 * j + c) * D_ + h * 32 + g * 8);

  const ushort* fragb = frag + ((size_t)bh * 64 + wid * 16) * 2048 + (size_t)lane * 8;
  const ushort* mb = maskp + (size_t)b * S_ + koff + g * 8;

  const f32x4 zero = {0.f, 0.f, 0.f, 0.f};
  f32x4 o0[8], o1[8], o2[8];
#pragma unroll
  for (int j = 0; j < 8; ++j) { o0[j] = zero; o1[j] = zero; o2[j] = zero; }

  bf16x8 ak0 = load8(fragb + 0 * 512);
  bf16x8 ak1 = load8(fragb + 1 * 512);
  bf16x8 av0 = load8(fragb + 2 * 512);
  bf16x8 av1 = load8(fragb + 3 * 512);
  bf16x8 am  = load8(mb);

  for (int t = 0; t < 16; ++t) {
    int tn = (t + 1) & 15;
    const ushort* fn = fragb + (size_t)tn * 2048;
    bf16x8 nk0 = load8(fn + 0 * 512);
    bf16x8 nk1 = load8(fn + 1 * 512);
    bf16x8 nv0 = load8(fn + 2 * 512);
    bf16x8 nv1 = load8(fn + 3 * 512);
    bf16x8 nm  = load8(mb + tn * 32);

#pragma unroll
    for (int j = 0; j < 8; ++j) {
      f32x4 s0 = __builtin_amdgcn_mfma_f32_16x16x32_bf16(ak0, fq[j], zero, 0, 0, 0);
      f32x4 s1 = __builtin_amdgcn_mfma_f32_16x16x32_bf16(ak1, fq[j], zero, 0, 0, 0);

      float p0 = __builtin_amdgcn_exp2f(s0[0]);
      float p1 = __builtin_amdgcn_exp2f(s0[1]);
      float p2 = __builtin_amdgcn_exp2f(s0[2]);
      float p3 = __builtin_amdgcn_exp2f(s0[3]);
      float p4 = __builtin_amdgcn_exp2f(s1[0]);
      float p5 = __builtin_amdgcn_exp2f(s1[1]);
      float p6 = __builtin_amdgcn_exp2f(s1[2]);
      float p7 = __builtin_amdgcn_exp2f(s1[3]);

      uint4 uw = make_uint4(cvtpk(p0, p1), cvtpk(p2, p3), cvtpk(p4, p5), cvtpk(p6, p7));
      bf16x8 fp = __builtin_bit_cast(bf16x8, uw);

      o0[j] = __builtin_amdgcn_mfma_f32_16x16x32_bf16(fp, av0, o0[j], 0, 0, 0);
      o1[j] = __builtin_amdgcn_mfma_f32_16x16x32_bf16(fp, av1, o1[j], 0, 0, 0);
      o2[j] = __builtin_amdgcn_mfma_f32_16x16x32_bf16(fp, am, o2[j], 0, 0, 0);
    }

    ak0 = nk0; ak1 = nk1; av0 = nv0; av1 = nv1; am = nm;
  }

  // deposit wave partials to LDS (bf16)
#pragma unroll
  for (int j = 0; j < 8; ++j) {
#pragma unroll
    for (int r = 0; r < 4; ++r) {
      int ql = 16 * j + 4 * g + r;
      lo[wid][ql][c] = f2bf(o0[j][r]);
      lo[wid][ql][16 + c] = f2bf(o1[j][r]);
      if (c == 0) ll[wid][ql] = o2[j][r];
    }
  }
  __syncthreads();
  if (tid < 128) {
    float l = ll[0][tid] + ll[1][tid] + ll[2][tid] + ll[3][tid];
    linv[tid] = 1.f / l;
  }
  __syncthreads();

  // reduce 4 wave-partials and write bf16 output (128 q rows)
  for (int e = tid; e < 128 * 32; e += 256) {
    int q = e >> 5, d = e & 31;
    float s = bf2f(lo[0][q][d]) + bf2f(lo[1][q][d]) + bf2f(lo[2][q][d]) + bf2f(lo[3][q][d]);
    attnbf[(size_t)(b * S_ + q0 + q) * D_ + h * 32 + d] = f2bf(s * linv[q]);
  }
}

// ---- projection GEMM (green verbatim) ----
__global__ __launch_bounds__(256) void proj_kernel(
    const ushort* __restrict__ attnbf,
    const ushort* __restrict__ wfrag,
    const float* __restrict__ bias,
    float* __restrict__ out) {
  __shared__ __align__(16) ushort sA[64][264];

  const int tid = threadIdx.x;
  const int wid = tid >> 6, lane = tid & 63;
  const int c = lane & 15, g = lane >> 4;
  const int mb0 = blockIdx.x * 64;
  const int m0 = mb0 + wid * 16;
  const int n0 = blockIdx.y * 64;

#pragma unroll
  for (int it = 0; it < 8; ++it) {
    int idx = tid + it * 256;
    int row = idx >> 5, c8 = idx & 31;
    uint4 v = *(const uint4*)(attnbf + (size_t)(mb0 + row) * D_ + c8 * 8);
    *(uint4*)(&sA[row][c8 * 8]) = v;
  }
  __syncthreads();

  f32x4 acc[4];
#pragma unroll
  for (int nb = 0; nb < 4; ++nb) acc[nb] = (f32x4){0.f, 0.f, 0.f, 0.f};

#pragma unroll
  for (int ks = 0; ks < 8; ++ks) {
    bf16x8 fa = load8(&sA[wid * 16 + c][ks * 32 + 8 * g]);
#pragma unroll
    for (int nb = 0; nb < 4; ++nb) {
      int nt = (n0 >> 4) + nb;
      bf16x8 fb = load8(wfrag + ((size_t)(nt * 8 + ks) * 64 + lane) * 8);
      acc[nb] = __builtin_amdgcn_mfma_f32_16x16x32_bf16(fa, fb, acc[nb], 0, 0, 0);
    }
  }

#pragma unroll
  for (int nb = 0; nb < 4; ++nb) {
    int n = n0 + nb * 16 + c;
    float bv = bias[n];
#pragma unroll
    for (int r = 0; r < 4; ++r) {
      int mrow = m0 + 4 * g + r;
      float v = acc[nb][r] + bv;
      out[(size_t)mrow * D_ + n] = fmaxf(v, 0.f);
    }
  }
}

extern "C" void kernel_launch(void* const* d_in, const int* in_sizes, int n_in,
                              void* d_out, int out_size, void* d_ws, size_t ws_size,
                              hipStream_t stream) {
  const float* x = (const float*)d_in[0];     // [B,S,D]
  const float* mask = (const float*)d_in[1];  // [B,S,1]
  const float* pos = (const float*)d_in[2];   // [B,S,D]
  const float* W = (const float*)d_in[3];     // [D,D]
  const float* bias = (const float*)d_in[4];  // [D]
  float* out = (float*)d_out;

  const size_t NE = (size_t)B_ * S_ * D_;  // 2097152
  // ws: posbf 4MB | frag 8MB | attnbf 4MB | wfrag 128KB | maskp 16KB
  ushort* posbf = (ushort*)d_ws;
  ushort* fragbuf = posbf + NE;                     // 4194304 elems
  ushort* attnbf = fragbuf + (size_t)4194304;
  ushort* wfragbuf = attnbf + NE;                   // D*D = 65536
  ushort* maskpbuf = wfragbuf + (size_t)D_ * D_;    // B*S = 8192

  prep_kernel<<<dim3(64, 33), 256, 0, stream>>>(x, mask, pos, W, posbf, fragbuf,
                                                maskpbuf, wfragbuf);
  attn_kernel<<<512, 256, 0, stream>>>(posbf, fragbuf, maskpbuf, attnbf);
  proj_kernel<<<dim3((B_ * S_) / 64, D_ / 64), 256, 0, stream>>>(attnbf, wfragbuf, bias, out);
}

// Round 23
// 42.425 us; speedup vs baseline: 1.0835x; 1.0835x over previous
//
#include <hip/hip_runtime.h>
#include <hip/hip_bf16.h>
#include <math.h>

#define B_ 4
#define S_ 2048
#define D_ 256
#define H_ 8

typedef __attribute__((ext_vector_type(8))) __bf16 bf16x8;
typedef __attribute__((ext_vector_type(4))) float f32x4;

__device__ inline ushort f2bf(float x) {
  unsigned u = __builtin_bit_cast(unsigned, x);
  unsigned r = u + 0x7fffu + ((u >> 16) & 1u);
  return (ushort)(r >> 16);
}

__device__ inline float bf2f(ushort u) {
  unsigned v = ((unsigned)u) << 16;
  return __builtin_bit_cast(float, v);
}

__device__ inline unsigned cvtpk(float lo, float hi) {
  unsigned r;
  asm("v_cvt_pk_bf16_f32 %0, %1, %2" : "=v"(r) : "v"(lo), "v"(hi));
  return r;
}

__device__ inline bf16x8 load8(const ushort* p) {
  return __builtin_bit_cast(bf16x8, *(const uint4*)p);
}

// sqrt(RS * log2e), RS = 1/32^0.25 ; scores from scaled Q,K are C1*s directly,
// and the old fixed offset -16*log2e is a global 2^-23 factor that cancels in o/l.
#define SC_ 0.7788317f

// ---- unified prepass: grid (64, 33).
//  bh<32 : posbf (scaled pos -> bf16), frag K/V, maskp
//  bh==32: W fragment tile T (ks=T&7, np=T>>3) -> wfrag
__global__ __launch_bounds__(256) void prep_kernel(
    const float* __restrict__ x, const float* __restrict__ mask,
    const float* __restrict__ pos, const float* __restrict__ w,
    ushort* __restrict__ posbf, ushort* __restrict__ frag,
    ushort* __restrict__ maskp, ushort* __restrict__ wfrag) {
  __shared__ float Lx[32][33];
  __shared__ ushort Wt[32][33];
  const int T = blockIdx.x, bh = blockIdx.y;
  const int tid = threadIdx.x;

  if (bh == 32) {
    int ks = T & 7, np = T >> 3;
    int k0 = ks * 32, n0 = np * 32;
#pragma unroll
    for (int k = 0; k < 4; ++k) {
      int idx = tid + k * 256;  // 0..1023
      int ty = idx >> 5, tx = idx & 31;
      Wt[ty][tx] = f2bf(w[(k0 + ty) * D_ + n0 + tx]);
    }
    __syncthreads();
    if (tid < 128) {
      int sub = tid >> 6, lane = tid & 63;
      int c = lane & 15, g = lane >> 4;
      int nt = np * 2 + sub;
      ushort e[8];
#pragma unroll
      for (int i = 0; i < 8; ++i) e[i] = Wt[g * 8 + i][sub * 16 + c];
      uint4 fr;
      fr.x = (unsigned)e[0] | ((unsigned)e[1] << 16);
      fr.y = (unsigned)e[2] | ((unsigned)e[3] << 16);
      fr.z = (unsigned)e[4] | ((unsigned)e[5] << 16);
      fr.w = (unsigned)e[6] | ((unsigned)e[7] << 16);
      *(uint4*)(wfrag + ((size_t)(nt * 8 + ks) * 64 + lane) * 8) = fr;
    }
    return;
  }

  const int b = bh >> 3, h = bh & 7;
  const int slot = tid >> 6, lane = tid & 63;
  const int c = lane & 15, g = lane >> 4;
  const size_t rb = (size_t)(b * S_) + T * 32;  // global row base

  // (a) x * mask -> LDS f32 tile (float4 loads)
  {
    int row = tid >> 3, c4 = tid & 7;
    float mv = mask[rb + row];
    float4 v = *(const float4*)(x + (rb + row) * D_ + h * 32 + c4 * 4);
    Lx[row][c4 * 4 + 0] = v.x * mv;
    Lx[row][c4 * 4 + 1] = v.y * mv;
    Lx[row][c4 * 4 + 2] = v.z * mv;
    Lx[row][c4 * 4 + 3] = v.w * mv;
  }

  // (b) K slots: pos scaled by SC_ (folds the softmax scale into Q and K)
  if (slot < 2) {
    int row = slot * 16 + c;
    const float* ps = pos + (rb + row) * D_ + h * 32 + g * 8;
    float4 v0 = *(const float4*)ps;
    float4 v1 = *(const float4*)(ps + 4);
    uint4 fr;
    fr.x = (unsigned)f2bf(v0.x * SC_) | ((unsigned)f2bf(v0.y * SC_) << 16);
    fr.y = (unsigned)f2bf(v0.z * SC_) | ((unsigned)f2bf(v0.w * SC_) << 16);
    fr.z = (unsigned)f2bf(v1.x * SC_) | ((unsigned)f2bf(v1.y * SC_) << 16);
    fr.w = (unsigned)f2bf(v1.z * SC_) | ((unsigned)f2bf(v1.w * SC_) << 16);
    *(uint4*)(frag + ((size_t)(bh * 64 + T) * 4 + slot) * 512 + lane * 8) = fr;
    *(uint4*)(posbf + (rb + row) * D_ + h * 32 + g * 8) = fr;
  }

  __syncthreads();

  // (c) V slots
  if (slot >= 2) {
    int dcol = (slot - 2) * 16 + c;
    ushort e[8];
#pragma unroll
    for (int i = 0; i < 8; ++i) {
      int key = (i < 4) ? (4 * g + i) : (16 + 4 * g + (i - 4));  // kappa(g*8+i)
      e[i] = f2bf(Lx[key][dcol]);
    }
    uint4 fr;
    fr.x = (unsigned)e[0] | ((unsigned)e[1] << 16);
    fr.y = (unsigned)e[2] | ((unsigned)e[3] << 16);
    fr.z = (unsigned)e[4] | ((unsigned)e[5] << 16);
    fr.w = (unsigned)e[6] | ((unsigned)e[7] << 16);
    *(uint4*)(frag + ((size_t)(bh * 64 + T) * 4 + slot) * 512 + lane * 8) = fr;
  }

  // (d) kappa-permuted bf16 mask
  if (h == 0 && tid < 32) {
    int t = tid;
    int kx = ((t >> 1) & 12) + (t & 3) + ((t & 4) << 2);
    maskp[rb + t] = f2bf(mask[rb + kx]);
  }
}

// ---- flash attention (frozen green structure; p = exp2(s) directly) ----
__global__ __launch_bounds__(256, 3) void attn_kernel(
    const ushort* __restrict__ posbf,
    const ushort* __restrict__ frag,
    const ushort* __restrict__ maskp,
    ushort* __restrict__ attnbf) {
  __shared__ ushort lo[4][64][32];
  __shared__ float ll[4][64];
  __shared__ float linv[64];

  const int tid = threadIdx.x;
  const int wid = tid >> 6, lane = tid & 63;
  const int c = lane & 15, g = lane >> 4;
  const int blk = blockIdx.x;
  const int bh = blk & 31;
  const int qc = blk >> 5;
  const int b = bh >> 3, h = bh & 7;
  const int q0 = qc * 64;
  const int koff = wid * 512;

  const ushort* posb = posbf + (size_t)b * S_ * D_;

  bf16x8 fq[4];
#pragma unroll
  for (int j = 0; j < 4; ++j)
    fq[j] = load8(posb + (size_t)(q0 + 16 * j + c) * D_ + h * 32 + g * 8);

  const ushort* fragb = frag + ((size_t)bh * 64 + wid * 16) * 2048 + (size_t)lane * 8;
  const ushort* mb = maskp + (size_t)b * S_ + koff + g * 8;

  const f32x4 zero = {0.f, 0.f, 0.f, 0.f};
  f32x4 o0[4], o1[4], o2[4];
#pragma unroll
  for (int j = 0; j < 4; ++j) { o0[j] = zero; o1[j] = zero; o2[j] = zero; }

  bf16x8 ak0 = load8(fragb + 0 * 512);
  bf16x8 ak1 = load8(fragb + 1 * 512);
  bf16x8 av0 = load8(fragb + 2 * 512);
  bf16x8 av1 = load8(fragb + 3 * 512);
  bf16x8 am  = load8(mb);

  for (int t = 0; t < 16; ++t) {
    int tn = (t + 1) & 15;
    const ushort* fn = fragb + (size_t)tn * 2048;
    bf16x8 nk0 = load8(fn + 0 * 512);
    bf16x8 nk1 = load8(fn + 1 * 512);
    bf16x8 nv0 = load8(fn + 2 * 512);
    bf16x8 nv1 = load8(fn + 3 * 512);
    bf16x8 nm  = load8(mb + tn * 32);

#pragma unroll
    for (int j = 0; j < 4; ++j) {
      f32x4 s0 = __builtin_amdgcn_mfma_f32_16x16x32_bf16(ak0, fq[j], zero, 0, 0, 0);
      f32x4 s1 = __builtin_amdgcn_mfma_f32_16x16x32_bf16(ak1, fq[j], zero, 0, 0, 0);

      float p0 = __builtin_amdgcn_exp2f(s0[0]);
      float p1 = __builtin_amdgcn_exp2f(s0[1]);
      float p2 = __builtin_amdgcn_exp2f(s0[2]);
      float p3 = __builtin_amdgcn_exp2f(s0[3]);
      float p4 = __builtin_amdgcn_exp2f(s1[0]);
      float p5 = __builtin_amdgcn_exp2f(s1[1]);
      float p6 = __builtin_amdgcn_exp2f(s1[2]);
      float p7 = __builtin_amdgcn_exp2f(s1[3]);

      uint4 uw = make_uint4(cvtpk(p0, p1), cvtpk(p2, p3), cvtpk(p4, p5), cvtpk(p6, p7));
      bf16x8 fp = __builtin_bit_cast(bf16x8, uw);

      o0[j] = __builtin_amdgcn_mfma_f32_16x16x32_bf16(fp, av0, o0[j], 0, 0, 0);
      o1[j] = __builtin_amdgcn_mfma_f32_16x16x32_bf16(fp, av1, o1[j], 0, 0, 0);
      o2[j] = __builtin_amdgcn_mfma_f32_16x16x32_bf16(fp, am, o2[j], 0, 0, 0);
    }

    ak0 = nk0; ak1 = nk1; av0 = nv0; av1 = nv1; am = nm;
  }

#pragma unroll
  for (int j = 0; j < 4; ++j) {
#pragma unroll
    for (int r = 0; r < 4; ++r) {
      int ql = 16 * j + 4 * g + r;
      lo[wid][ql][c] = f2bf(o0[j][r]);
      lo[wid][ql][16 + c] = f2bf(o1[j][r]);
      if (c == 0) ll[wid][ql] = o2[j][r];
    }
  }
  __syncthreads();
  if (tid < 64) {
    float l = ll[0][tid] + ll[1][tid] + ll[2][tid] + ll[3][tid];
    linv[tid] = 1.f / l;
  }
  __syncthreads();

  for (int e = tid; e < 64 * 32; e += 256) {
    int q = e >> 5, d = e & 31;
    float s = bf2f(lo[0][q][d]) + bf2f(lo[1][q][d]) + bf2f(lo[2][q][d]) + bf2f(lo[3][q][d]);
    attnbf[(size_t)(b * S_ + q0 + q) * D_ + h * 32 + d] = f2bf(s * linv[q]);
  }
}

// ---- projection GEMM (green verbatim) ----
__global__ __launch_bounds__(256) void proj_kernel(
    const ushort* __restrict__ attnbf,
    const ushort* __restrict__ wfrag,
    const float* __restrict__ bias,
    float* __restrict__ out) {
  __shared__ __align__(16) ushort sA[64][264];

  const int tid = threadIdx.x;
  const int wid = tid >> 6, lane = tid & 63;
  const int c = lane & 15, g = lane >> 4;
  const int mb0 = blockIdx.x * 64;
  const int m0 = mb0 + wid * 16;
  const int n0 = blockIdx.y * 64;

#pragma unroll
  for (int it = 0; it < 8; ++it) {
    int idx = tid + it * 256;
    int row = idx >> 5, c8 = idx & 31;
    uint4 v = *(const uint4*)(attnbf + (size_t)(mb0 + row) * D_ + c8 * 8);
    *(uint4*)(&sA[row][c8 * 8]) = v;
  }
  __syncthreads();

  f32x4 acc[4];
#pragma unroll
  for (int nb = 0; nb < 4; ++nb) acc[nb] = (f32x4){0.f, 0.f, 0.f, 0.f};

#pragma unroll
  for (int ks = 0; ks < 8; ++ks) {
    bf16x8 fa = load8(&sA[wid * 16 + c][ks * 32 + 8 * g]);
#pragma unroll
    for (int nb = 0; nb < 4; ++nb) {
      int nt = (n0 >> 4) + nb;
      bf16x8 fb = load8(wfrag + ((size_t)(nt * 8 + ks) * 64 + lane) * 8);
      acc[nb] = __builtin_amdgcn_mfma_f32_16x16x32_bf16(fa, fb, acc[nb], 0, 0, 0);
    }
  }

#pragma unroll
  for (int nb = 0; nb < 4; ++nb) {
    int n = n0 + nb * 16 + c;
    float bv = bias[n];
#pragma unroll
    for (int r = 0; r < 4; ++r) {
      int mrow = m0 + 4 * g + r;
      float v = acc[nb][r] + bv;
      out[(size_t)mrow * D_ + n] = fmaxf(v, 0.f);
    }
  }
}

extern "C" void kernel_launch(void* const* d_in, const int* in_sizes, int n_in,
                              void* d_out, int out_size, void* d_ws, size_t ws_size,
                              hipStream_t stream) {
  const float* x = (const float*)d_in[0];     // [B,S,D]
  const float* mask = (const float*)d_in[1];  // [B,S,1]
  const float* pos = (const float*)d_in[2];   // [B,S,D]
  const float* W = (const float*)d_in[3];     // [D,D]
  const float* bias = (const float*)d_in[4];  // [D]
  float* out = (float*)d_out;

  const size_t NE = (size_t)B_ * S_ * D_;  // 2097152
  // ws: posbf 4MB | frag 8MB | attnbf 4MB | wfrag 128KB | maskp 16KB
  ushort* posbf = (ushort*)d_ws;
  ushort* fragbuf = posbf + NE;                     // 4194304 elems
  ushort* attnbf = fragbuf + (size_t)4194304;
  ushort* wfragbuf = attnbf + NE;                   // D*D = 65536
  ushort* maskpbuf = wfragbuf + (size_t)D_ * D_;    // B*S = 8192

  prep_kernel<<<dim3(64, 33), 256, 0, stream>>>(x, mask, pos, W, posbf, fragbuf,
                                                maskpbuf, wfragbuf);
  attn_kernel<<<1024, 256, 0, stream>>>(posbf, fragbuf, maskpbuf, attnbf);
  proj_kernel<<<dim3((B_ * S_) / 64, D_ / 64), 256, 0, stream>>>(attnbf, wfragbuf, bias, out);
}